// Round 1
// baseline (66.686 us; speedup 1.0000x reference)
//
#include <hip/hip_runtime.h>
#include <cstdint>
#include <cstddef>

#define NB 32768      // batch rows
#define KI 512        // input dim
#define NE 8          // experts
#define NX 128        // expert output dim
#define NT 2          // tasks
#define NWD 64        // tower hidden width
#define BM 128        // rows per block
#define THREADS 512
#define SMEM_BYTES 163840
#define W2_BYTES (NE * KI * NX * 2)   /* 1 MiB repacked bf16 We */

typedef __attribute__((ext_vector_type(8))) short bf16x8;
typedef __attribute__((ext_vector_type(4))) float f32x4;

__device__ __forceinline__ unsigned short f2bf(float f) {
  union { float f; unsigned u; } v; v.f = f;
  return (unsigned short)((v.u + 0x7fffu + ((v.u >> 16) & 1u)) >> 16);
}

#define AS1(p) ((const __attribute__((address_space(1))) void*)(uintptr_t)(p))
#define AS3(p) ((__attribute__((address_space(3))) void*)(uintptr_t)(p))

// Repack We f32 [E][I][X] -> bf16 W2 in MFMA-B fragment order: [e][kblk(64)][col(128)][8k]
__global__ __launch_bounds__(256) void repack_we_kernel(const float* __restrict__ We,
                                                        unsigned short* __restrict__ W2) {
  int tid = blockIdx.x * 256 + threadIdx.x;  // 65536 total
  int col  = tid & (NX - 1);
  int kblk = (tid >> 7) & 63;
  int e    = tid >> 13;
  const float* src = We + ((size_t)e * KI + (size_t)kblk * 8) * NX + col;
  bf16x8 v;
#pragma unroll
  for (int j = 0; j < 8; ++j) v[j] = (short)f2bf(src[(size_t)j * NX]);
  *(bf16x8*)(W2 + (size_t)tid * 8) = v;
}

template <bool USE_WS>
__global__ __launch_bounds__(THREADS, 2)
void moe_fused_kernel(const float* __restrict__ x, const float* __restrict__ We,
                      const float* __restrict__ be, const float* __restrict__ gates,
                      const float* __restrict__ tW1, const float* __restrict__ tb1,
                      const float* __restrict__ tW2, const float* __restrict__ tb2,
                      const unsigned short* __restrict__ W2, float* __restrict__ out) {
  extern __shared__ char smem[];
  // LDS map: [0,131072)  x tile [128 rows][512 k] bf16, 16B-XOR swizzled per row
  //          [131072,163840) W double buffer: 2 x [8 kblk][128 col][16B]
  // After expert loop, [0,65536) is reused for shared (tower A): [t][128 rows][128 k] bf16.
  char* wbuf = smem + 131072;

  const int tid  = threadIdx.x;
  const int lane = tid & 63;
  const int wid  = tid >> 6;        // 8 waves; wave owns rows wid*16..+15
  const int l15  = lane & 15;
  const int lhi  = lane >> 4;       // 0..3
  const int row0 = blockIdx.x * BM;

  f32x4 acc[8];
  f32x4 shacc[NT][8];
  f32x4 gacc = {0.f, 0.f, 0.f, 0.f};
#pragma unroll
  for (int t = 0; t < NT; ++t)
#pragma unroll
    for (int cf = 0; cf < 8; ++cf) shacc[t][cf] = (f32x4){0.f, 0.f, 0.f, 0.f};

  const int arow = wid * 16 + l15;          // this lane's A row
  const int asw  = (arow & 7) << 4;
  char* abase = smem + arow * 1024;

  // ---- stage one x chunk (BK=64 f32 cols) into swizzled bf16 LDS ----
  auto stage_x = [&](int kk) {
    const int xr = tid >> 2;   // 0..127
    const int xs = tid & 3;    // 16 floats each
    const float* src = x + (size_t)(row0 + xr) * KI + kk * 64 + xs * 16;
    float4 a0 = ((const float4*)src)[0];
    float4 a1 = ((const float4*)src)[1];
    float4 a2 = ((const float4*)src)[2];
    float4 a3 = ((const float4*)src)[3];
    bf16x8 v0, v1;
    v0[0]=(short)f2bf(a0.x); v0[1]=(short)f2bf(a0.y); v0[2]=(short)f2bf(a0.z); v0[3]=(short)f2bf(a0.w);
    v0[4]=(short)f2bf(a1.x); v0[5]=(short)f2bf(a1.y); v0[6]=(short)f2bf(a1.z); v0[7]=(short)f2bf(a1.w);
    v1[0]=(short)f2bf(a2.x); v1[1]=(short)f2bf(a2.y); v1[2]=(short)f2bf(a2.z); v1[3]=(short)f2bf(a2.w);
    v1[4]=(short)f2bf(a3.x); v1[5]=(short)f2bf(a3.y); v1[6]=(short)f2bf(a3.z); v1[7]=(short)f2bf(a3.w);
    const int sw = (xr & 7) << 4;
    const int kb = kk * 128 + xs * 32;
    *(bf16x8*)(smem + xr * 1024 + ((kb) ^ sw)) = v0;
    *(bf16x8*)(smem + xr * 1024 + ((kb + 16) ^ sw)) = v1;
  };

  // ---- stage one We chunk (expert e, k-chunk kk) into wbuf[b] ----
  auto stage_w = [&](int e, int kk, int b) {
    if constexpr (USE_WS) {
      const char* gbase = (const char*)W2 + ((size_t)(e * 64 + kk * 8) * NX) * 16;
      char* lbase = wbuf + b * 16384 + wid * 1024;
      __builtin_amdgcn_global_load_lds(AS1(gbase + (wid * 64 + lane) * 16), AS3(lbase), 16, 0, 0);
      __builtin_amdgcn_global_load_lds(AS1(gbase + 8192 + (wid * 64 + lane) * 16), AS3(lbase + 8192), 16, 0, 0);
    } else {
      const int col = tid & 127;
      const int kb0 = tid >> 7;  // 0..3
#pragma unroll
      for (int h = 0; h < 2; ++h) {
        const int kblk = kb0 + h * 4;
        const float* src = We + ((size_t)e * KI + (size_t)(kk * 64 + kblk * 8)) * NX + col;
        bf16x8 v;
#pragma unroll
        for (int j = 0; j < 8; ++j) v[j] = (short)f2bf(src[(size_t)j * NX]);
        *(bf16x8*)(wbuf + b * 16384 + (kblk * NX + col) * 16) = v;
      }
    }
  };

  auto compute_chunk = [&](int kk, int b) {
#pragma unroll
    for (int ks = 0; ks < 2; ++ks) {
      bf16x8 a = *(const bf16x8*)(abase + ((kk * 128 + ks * 64 + lhi * 16) ^ asw));
      const char* bbase = wbuf + b * 16384 + ((ks * 4 + lhi) * NX + l15) * 16;
#pragma unroll
      for (int cf = 0; cf < 8; ++cf) {
        bf16x8 bfr = *(const bf16x8*)(bbase + cf * 256);
        acc[cf] = __builtin_amdgcn_mfma_f32_16x16x32_bf16(a, bfr, acc[cf], 0, 0, 0);
      }
    }
  };

  // g[t,e] for this wave's 16 rows; B gathered from gates f32 (L1-resident, 32 KB)
  auto compute_g = [&]() {
    const int ct = l15 >> 3;  // task
    const int ce = l15 & 7;   // expert
#pragma unroll
    for (int ks = 0; ks < 16; ++ks) {
      bf16x8 a = *(const bf16x8*)(abase + ((ks * 64 + lhi * 16) ^ asw));
      const float* gsrc = gates + (size_t)ct * (KI * NE) + (size_t)(ks * 32 + lhi * 8) * NE + ce;
      bf16x8 bv;
#pragma unroll
      for (int j = 0; j < 8; ++j) bv[j] = (short)f2bf(gsrc[j * NE]);
      gacc = __builtin_amdgcn_mfma_f32_16x16x32_bf16(a, bv, gacc, 0, 0, 0);
    }
  };

  // relu(+be) then shared += g*ex ; g redistributed via shfl (C-frag rows == acc rows)
  auto epilogue = [&](int e) {
    float gv[NT][4];
#pragma unroll
    for (int t = 0; t < NT; ++t)
#pragma unroll
      for (int r = 0; r < 4; ++r)
        gv[t][r] = __shfl(gacc[r], (lane & 48) | (t * 8 + e), 64);
#pragma unroll
    for (int cf = 0; cf < 8; ++cf) {
      const float bev = be[e * NX + cf * 16 + l15];
#pragma unroll
      for (int r = 0; r < 4; ++r) {
        float ex = acc[cf][r] + bev;
        ex = fmaxf(ex, 0.f);
        shacc[0][cf][r] += gv[0][r] * ex;
        shacc[1][cf][r] += gv[1][r] * ex;
      }
    }
  };

  // ================= main expert loop =================
  for (int e = 0; e < NE; ++e) {
#pragma unroll
    for (int cf = 0; cf < 8; ++cf) acc[cf] = (f32x4){0.f, 0.f, 0.f, 0.f};
    if (e == 0) stage_x(0);
    stage_w(e, 0, 0);
    __syncthreads();
    for (int kk = 0; kk < 8; ++kk) {
      if (kk < 7) {
        if (e == 0) stage_x(kk + 1);
        stage_w(e, kk + 1, (kk + 1) & 1);
      }
      compute_chunk(kk, kk & 1);
      __syncthreads();
    }
    if (e == 0) compute_g();
    epilogue(e);
  }

  // ================= tower =================
  // write shared (bf16, swizzled) into dead x region
#pragma unroll
  for (int t = 0; t < NT; ++t)
#pragma unroll
    for (int cf = 0; cf < 8; ++cf)
#pragma unroll
      for (int r = 0; r < 4; ++r) {
        const int rr = wid * 16 + lhi * 4 + r;
        const int cc = cf * 16 + l15;
        *(unsigned short*)(smem + t * 32768 + rr * 256 + ((cc * 2) ^ ((rr & 7) << 4))) =
            f2bf(shacc[t][cf][r]);
      }
  __syncthreads();

#pragma unroll
  for (int t = 0; t < NT; ++t) {
    f32x4 hacc[4];
#pragma unroll
    for (int cf = 0; cf < 4; ++cf) hacc[cf] = (f32x4){0.f, 0.f, 0.f, 0.f};
    const int trow = wid * 16 + l15;
    const char* tbase = smem + t * 32768 + trow * 256;
    const int tsw = (trow & 7) << 4;
#pragma unroll
    for (int ks = 0; ks < 4; ++ks) {
      bf16x8 a = *(const bf16x8*)(tbase + ((ks * 64 + lhi * 16) ^ tsw));
#pragma unroll
      for (int cf = 0; cf < 4; ++cf) {
        const int col = cf * 16 + l15;
        const float* wsrc = tW1 + (size_t)t * (NX * NWD) + (size_t)(ks * 32 + lhi * 8) * NWD + col;
        bf16x8 bv;
#pragma unroll
        for (int j = 0; j < 8; ++j) bv[j] = (short)f2bf(wsrc[j * NWD]);
        hacc[cf] = __builtin_amdgcn_mfma_f32_16x16x32_bf16(a, bv, hacc[cf], 0, 0, 0);
      }
    }
    float p[4] = {0.f, 0.f, 0.f, 0.f};
#pragma unroll
    for (int cf = 0; cf < 4; ++cf) {
      const int col = cf * 16 + l15;
      const float b1 = tb1[t * NWD + col];
      const float w2 = tW2[t * NWD + col];
#pragma unroll
      for (int r = 0; r < 4; ++r) {
        float h = fmaxf(hacc[cf][r] + b1, 0.f);
        p[r] += h * w2;
      }
    }
#pragma unroll
    for (int r = 0; r < 4; ++r) {
      p[r] += __shfl_xor(p[r], 1, 64);
      p[r] += __shfl_xor(p[r], 2, 64);
      p[r] += __shfl_xor(p[r], 4, 64);
      p[r] += __shfl_xor(p[r], 8, 64);
    }
    if (l15 == 0) {
      const float b2 = tb2[t];
#pragma unroll
      for (int r = 0; r < 4; ++r)
        out[(size_t)t * NB + row0 + wid * 16 + lhi * 4 + r] = p[r] + b2;
    }
  }
}

extern "C" void kernel_launch(void* const* d_in, const int* in_sizes, int n_in,
                              void* d_out, int out_size, void* d_ws, size_t ws_size,
                              hipStream_t stream) {
  const float* x     = (const float*)d_in[0];
  const float* We    = (const float*)d_in[1];
  const float* be    = (const float*)d_in[2];
  const float* gates = (const float*)d_in[3];
  const float* tW1   = (const float*)d_in[4];
  const float* tb1   = (const float*)d_in[5];
  const float* tW2   = (const float*)d_in[6];
  const float* tb2   = (const float*)d_in[7];
  float* out = (float*)d_out;

  const bool use_ws = (d_ws != nullptr) && (ws_size >= (size_t)W2_BYTES);
  const int nblk = NB / BM;  // 256

  if (use_ws) {
    unsigned short* W2 = (unsigned short*)d_ws;
    hipFuncSetAttribute(reinterpret_cast<const void*>(moe_fused_kernel<true>),
                        hipFuncAttributeMaxDynamicSharedMemorySize, SMEM_BYTES);
    repack_we_kernel<<<(NE * KI * NX / 8) / 256, 256, 0, stream>>>(We, W2);
    moe_fused_kernel<true><<<nblk, THREADS, SMEM_BYTES, stream>>>(
        x, We, be, gates, tW1, tb1, tW2, tb2, W2, out);
  } else {
    hipFuncSetAttribute(reinterpret_cast<const void*>(moe_fused_kernel<false>),
                        hipFuncAttributeMaxDynamicSharedMemorySize, SMEM_BYTES);
    moe_fused_kernel<false><<<nblk, THREADS, SMEM_BYTES, stream>>>(
        x, We, be, gates, tW1, tb1, tW2, tb2, nullptr, out);
  }
}